// Round 1
// baseline (1013.768 us; speedup 1.0000x reference)
//
#include <hip/hip_runtime.h>

#define D 64

__device__ __forceinline__ float relu_f(float v) { return v > 0.f ? v : 0.f; }

// x0[e][:] = fact_emb[edge_type[e]][:]; x = x0
__global__ void k_gather(const int* __restrict__ et, const float* __restrict__ fe,
                         float* __restrict__ x0, float* __restrict__ x, int E) {
    int u = blockIdx.x * blockDim.x + threadIdx.x;
    if (u >= E * 16) return;
    int e = u >> 4, q = u & 15;
    float4 v = reinterpret_cast<const float4*>(fe + (size_t)et[e] * D)[q];
    reinterpret_cast<float4*>(x0 + (size_t)e * D)[q] = v;
    reinterpret_cast<float4*>(x  + (size_t)e * D)[q] = v;
}

// agg[ac[t]][:] += x[ab[t]][:] * x[bc[t]][:]   (atomic scatter)
__global__ void k_scatter(const int* __restrict__ ab, const int* __restrict__ bc,
                          const int* __restrict__ ac, const float* __restrict__ x,
                          float* __restrict__ agg, int T) {
    int u = blockIdx.x * blockDim.x + threadIdx.x;
    if (u >= T * 16) return;
    int t = u >> 4, q = u & 15;
    int ea = ab[t], eb = bc[t], ec = ac[t];
    float4 a = reinterpret_cast<const float4*>(x + (size_t)ea * D)[q];
    float4 b = reinterpret_cast<const float4*>(x + (size_t)eb * D)[q];
    float* dst = agg + (size_t)ec * D + q * 4;
    atomicAdd(dst + 0, a.x * b.x);
    atomicAdd(dst + 1, a.y * b.y);
    atomicAdd(dst + 2, a.z * b.z);
    atomicAdd(dst + 3, a.w * b.w);
}

// outx = relu(in @ W + b), in: [E,64], W: [64,64] row-major
// block = 256 threads, 64 rows/block, each thread computes 4 rows x 4 cols
#define FPAD 68
__global__ __launch_bounds__(256) void k_linear(const float* __restrict__ in,
        const float* __restrict__ W, const float* __restrict__ b,
        float* __restrict__ outx, int E) {
    __shared__ float Wl[64 * 64];       // 16 KB
    __shared__ float fT[64 * FPAD];     // fT[k][r], 17.4 KB
    const int tid = threadIdx.x;
    const int row0 = blockIdx.x * 64;

    for (int i = tid; i < 1024; i += 256)
        reinterpret_cast<float4*>(Wl)[i] = reinterpret_cast<const float4*>(W)[i];

    for (int i = tid; i < 1024; i += 256) {
        int r = i >> 4, q = i & 15;
        float4 v = make_float4(0.f, 0.f, 0.f, 0.f);
        if (row0 + r < E)
            v = reinterpret_cast<const float4*>(in + (size_t)(row0 + r) * D)[q];
        fT[(q * 4 + 0) * FPAD + r] = v.x;
        fT[(q * 4 + 1) * FPAD + r] = v.y;
        fT[(q * 4 + 2) * FPAD + r] = v.z;
        fT[(q * 4 + 3) * FPAD + r] = v.w;
    }
    __syncthreads();

    const int j0 = (tid & 15) * 4;
    const int r0 = (tid >> 4) * 4;
    float acc[4][4];
    #pragma unroll
    for (int i = 0; i < 4; ++i)
        #pragma unroll
        for (int j = 0; j < 4; ++j) acc[i][j] = 0.f;

    #pragma unroll 8
    for (int k = 0; k < 64; ++k) {
        float4 f = *reinterpret_cast<const float4*>(&fT[k * FPAD + r0]);
        float4 w = *reinterpret_cast<const float4*>(&Wl[k * 64 + j0]);
        float fa[4] = {f.x, f.y, f.z, f.w};
        float wa[4] = {w.x, w.y, w.z, w.w};
        #pragma unroll
        for (int i = 0; i < 4; ++i)
            #pragma unroll
            for (int j = 0; j < 4; ++j) acc[i][j] += fa[i] * wa[j];
    }

    float4 bv = *reinterpret_cast<const float4*>(&b[j0]);
    float ba[4] = {bv.x, bv.y, bv.z, bv.w};
    #pragma unroll
    for (int i = 0; i < 4; ++i) {
        int row = row0 + r0 + i;
        if (row < E) {
            float4 o;
            o.x = relu_f(acc[i][0] + ba[0]);
            o.y = relu_f(acc[i][1] + ba[1]);
            o.z = relu_f(acc[i][2] + ba[2]);
            o.w = relu_f(acc[i][3] + ba[3]);
            *reinterpret_cast<float4*>(outx + (size_t)row * D + j0) = o;
        }
    }
}

// out[e] = relu(concat(x[e], x0[e]) @ W1 + b1) @ W2 + b2
// block = 512 threads, 64 rows/block, each thread 4 rows x 4 hidden cols
#define MPAD 68
__global__ __launch_bounds__(512) void k_mlp(const float* __restrict__ x,
        const float* __restrict__ x0, const float* __restrict__ W1,
        const float* __restrict__ b1, const float* __restrict__ W2,
        const float* __restrict__ b2, float* __restrict__ out, int E) {
    __shared__ float W1l[128 * 128];    // 64 KB
    __shared__ float fT[128 * MPAD];    // 34.8 KB, fT[k][r]
    __shared__ float b1l[128];
    __shared__ float W2l[128];
    const int tid = threadIdx.x;
    const int row0 = blockIdx.x * 64;

    for (int i = tid; i < 4096; i += 512)
        reinterpret_cast<float4*>(W1l)[i] = reinterpret_cast<const float4*>(W1)[i];
    if (tid < 128) { b1l[tid] = b1[tid]; W2l[tid] = W2[tid]; }

    // stage features transposed: k<64 from x, k>=64 from x0
    for (int i = tid; i < 2048; i += 512) {
        int r = i >> 5, q = i & 31;
        int qq = q & 15;
        const float* src = (q < 16) ? x : x0;
        float4 v = make_float4(0.f, 0.f, 0.f, 0.f);
        if (row0 + r < E)
            v = reinterpret_cast<const float4*>(src + (size_t)(row0 + r) * D)[qq];
        int kb = ((q < 16) ? 0 : 64) + qq * 4;
        fT[(kb + 0) * MPAD + r] = v.x;
        fT[(kb + 1) * MPAD + r] = v.y;
        fT[(kb + 2) * MPAD + r] = v.z;
        fT[(kb + 3) * MPAD + r] = v.w;
    }
    __syncthreads();

    const int jt = tid & 31;
    const int j0 = jt * 4;
    const int r0 = (tid >> 5) * 4;
    float acc[4][4];
    #pragma unroll
    for (int i = 0; i < 4; ++i)
        #pragma unroll
        for (int j = 0; j < 4; ++j) acc[i][j] = 0.f;

    #pragma unroll 8
    for (int k = 0; k < 128; ++k) {
        float4 f = *reinterpret_cast<const float4*>(&fT[k * MPAD + r0]);
        float4 w = *reinterpret_cast<const float4*>(&W1l[k * 128 + j0]);
        float fa[4] = {f.x, f.y, f.z, f.w};
        float wa[4] = {w.x, w.y, w.z, w.w};
        #pragma unroll
        for (int i = 0; i < 4; ++i)
            #pragma unroll
            for (int j = 0; j < 4; ++j) acc[i][j] += fa[i] * wa[j];
    }

    float4 bv = *reinterpret_cast<const float4*>(&b1l[j0]);
    float4 w2 = *reinterpret_cast<const float4*>(&W2l[j0]);
    float bias2 = b2[0];
    #pragma unroll
    for (int i = 0; i < 4; ++i) {
        float h0 = relu_f(acc[i][0] + bv.x);
        float h1 = relu_f(acc[i][1] + bv.y);
        float h2 = relu_f(acc[i][2] + bv.z);
        float h3 = relu_f(acc[i][3] + bv.w);
        float p = h0 * w2.x + h1 * w2.y + h2 * w2.z + h3 * w2.w;
        #pragma unroll
        for (int m = 1; m < 32; m <<= 1) p += __shfl_xor(p, m, 64);
        if (jt == 0) {
            int row = row0 + r0 + i;
            if (row < E) out[row] = p + bias2;
        }
    }
}

extern "C" void kernel_launch(void* const* d_in, const int* in_sizes, int n_in,
                              void* d_out, int out_size, void* d_ws, size_t ws_size,
                              hipStream_t stream) {
    const int*   edge_type = (const int*)d_in[0];
    const int*   ab        = (const int*)d_in[1];
    const int*   bc        = (const int*)d_in[2];
    const int*   ac        = (const int*)d_in[3];
    const float* fe        = (const float*)d_in[4];
    const float* W1        = (const float*)d_in[5];
    const float* b1        = (const float*)d_in[6];
    const float* W2        = (const float*)d_in[7];
    const float* b2        = (const float*)d_in[8];
    const float* mW1       = (const float*)d_in[9];
    const float* mb1       = (const float*)d_in[10];
    const float* mW2       = (const float*)d_in[11];
    const float* mb2       = (const float*)d_in[12];

    const int E = in_sizes[0];
    const int T = in_sizes[1];
    float* out = (float*)d_out;

    float* x0  = (float*)d_ws;
    float* x   = x0 + (size_t)E * D;
    float* agg = x  + (size_t)E * D;

    k_gather<<<(E * 16 + 255) / 256, 256, 0, stream>>>(edge_type, fe, x0, x, E);

    for (int layer = 0; layer < 2; ++layer) {
        const float* W = (layer == 0) ? W1 : W2;
        const float* b = (layer == 0) ? b1 : b2;
        hipMemsetAsync(agg, 0, (size_t)E * D * sizeof(float), stream);
        k_scatter<<<(T * 16 + 255) / 256, 256, 0, stream>>>(ab, bc, ac, x, agg, T);
        k_linear<<<(E + 63) / 64, 256, 0, stream>>>(agg, W, b, x, E);
    }

    k_mlp<<<(E + 63) / 64, 512, 0, stream>>>(x, x0, mW1, mb1, mW2, mb2, out, E);
}

// Round 2
// 277.550 us; speedup vs baseline: 3.6526x; 3.6526x over previous
//
#include <hip/hip_runtime.h>

#define D 64

__device__ __forceinline__ float relu_f(float v) { return v > 0.f ? v : 0.f; }

// x0[e][:] = fact_emb[edge_type[e]][:]; x = x0
__global__ void k_gather(const int* __restrict__ et, const float* __restrict__ fe,
                         float* __restrict__ x0, float* __restrict__ x, int E) {
    int u = blockIdx.x * blockDim.x + threadIdx.x;
    if (u >= E * 16) return;
    int e = u >> 4, q = u & 15;
    float4 v = reinterpret_cast<const float4*>(fe + (size_t)et[e] * D)[q];
    reinterpret_cast<float4*>(x0 + (size_t)e * D)[q] = v;
    reinterpret_cast<float4*>(x  + (size_t)e * D)[q] = v;
}

// ---------------- CSR build: histogram + scan + permute ----------------

__global__ void k_hist(const int* __restrict__ ac, int* __restrict__ cnt, int T) {
    int t = blockIdx.x * blockDim.x + threadIdx.x;
    if (t < T) atomicAdd(&cnt[ac[t]], 1);
}

// Pass A: per-block (1024 elems) exclusive scan; write local excl + block sums
__global__ __launch_bounds__(256) void k_scanA(const int* __restrict__ cnt,
        int* __restrict__ localExcl, int* __restrict__ blockSums, int E) {
    __shared__ int ls[256];
    const int tid = threadIdx.x;
    int base = blockIdx.x * 1024 + tid * 4;
    int a0 = 0, a1 = 0, a2 = 0, a3 = 0;
    if (base + 3 < E) {
        int4 v = *reinterpret_cast<const int4*>(cnt + base);
        a0 = v.x; a1 = v.y; a2 = v.z; a3 = v.w;
    } else {
        if (base + 0 < E) a0 = cnt[base + 0];
        if (base + 1 < E) a1 = cnt[base + 1];
        if (base + 2 < E) a2 = cnt[base + 2];
        if (base + 3 < E) a3 = cnt[base + 3];
    }
    int tsum = a0 + a1 + a2 + a3;
    ls[tid] = tsum;
    __syncthreads();
    for (int off = 1; off < 256; off <<= 1) {
        int v = (tid >= off) ? ls[tid - off] : 0;
        __syncthreads();
        ls[tid] += v;
        __syncthreads();
    }
    int excl = ls[tid] - tsum;
    if (tid == 255) blockSums[blockIdx.x] = ls[255];
    if (base + 3 < E) {
        int4 o = make_int4(excl, excl + a0, excl + a0 + a1, excl + a0 + a1 + a2);
        *reinterpret_cast<int4*>(localExcl + base) = o;
    } else {
        int run = excl;
        if (base + 0 < E) { localExcl[base + 0] = run; run += a0; }
        if (base + 1 < E) { localExcl[base + 1] = run; run += a1; }
        if (base + 2 < E) { localExcl[base + 2] = run; run += a2; }
        if (base + 3 < E) { localExcl[base + 3] = run; }
    }
}

// Pass B: single block scans block sums (n <= 256)
__global__ __launch_bounds__(256) void k_scanB(int* __restrict__ blockSums, int n) {
    __shared__ int ls[256];
    const int tid = threadIdx.x;
    int v = (tid < n) ? blockSums[tid] : 0;
    ls[tid] = v;
    __syncthreads();
    for (int off = 1; off < 256; off <<= 1) {
        int w = (tid >= off) ? ls[tid - off] : 0;
        __syncthreads();
        ls[tid] += w;
        __syncthreads();
    }
    if (tid < n) blockSums[tid] = ls[tid] - v;   // exclusive
}

// Pass C: start[i] = localExcl[i] + blockSums[i/1024]; cursor = start
__global__ void k_scanC(int* __restrict__ startArr, const int* __restrict__ blockSums,
                        int* __restrict__ cursor, int E) {
    int i = blockIdx.x * blockDim.x + threadIdx.x;
    if (i < E) {
        int s = startArr[i] + blockSums[i >> 10];
        startArr[i] = s;
        cursor[i] = s;
    }
}

__global__ void k_permute(const int* __restrict__ ab, const int* __restrict__ bc,
                          const int* __restrict__ ac, int* __restrict__ cursor,
                          int* __restrict__ sab, int* __restrict__ sbc, int T) {
    int t = blockIdx.x * blockDim.x + threadIdx.x;
    if (t >= T) return;
    int pos = atomicAdd(&cursor[ac[t]], 1);
    sab[pos] = ab[t];
    sbc[pos] = bc[t];
}

// ---------------- gather-based message aggregation ----------------
// one wave per edge e: agg[e][lane] = sum over triangles of x[ab][lane]*x[bc][lane]
__global__ __launch_bounds__(256) void k_gather_msg(const int* __restrict__ startArr,
        const int* __restrict__ cnt, const int* __restrict__ sab,
        const int* __restrict__ sbc, const float* __restrict__ x,
        float* __restrict__ agg, int E) {
    int e = blockIdx.x * (blockDim.x >> 6) + (threadIdx.x >> 6);
    if (e >= E) return;
    int lane = threadIdx.x & 63;
    int s = startArr[e], c = cnt[e];
    float acc = 0.f;
    int i = 0;
    for (; i + 1 < c; i += 2) {
        int ea0 = sab[s + i],     eb0 = sbc[s + i];
        int ea1 = sab[s + i + 1], eb1 = sbc[s + i + 1];
        float p0 = x[(size_t)ea0 * D + lane] * x[(size_t)eb0 * D + lane];
        float p1 = x[(size_t)ea1 * D + lane] * x[(size_t)eb1 * D + lane];
        acc += p0 + p1;
    }
    if (i < c) {
        int ea = sab[s + i], eb = sbc[s + i];
        acc += x[(size_t)ea * D + lane] * x[(size_t)eb * D + lane];
    }
    agg[(size_t)e * D + lane] = acc;
}

// ---------------- dense layers ----------------

// outx = relu(in @ W + b), in: [E,64], W: [64,64] row-major
#define FPAD 68
__global__ __launch_bounds__(256) void k_linear(const float* __restrict__ in,
        const float* __restrict__ W, const float* __restrict__ b,
        float* __restrict__ outx, int E) {
    __shared__ float Wl[64 * 64];
    __shared__ float fT[64 * FPAD];
    const int tid = threadIdx.x;
    const int row0 = blockIdx.x * 64;

    for (int i = tid; i < 1024; i += 256)
        reinterpret_cast<float4*>(Wl)[i] = reinterpret_cast<const float4*>(W)[i];

    for (int i = tid; i < 1024; i += 256) {
        int r = i >> 4, q = i & 15;
        float4 v = make_float4(0.f, 0.f, 0.f, 0.f);
        if (row0 + r < E)
            v = reinterpret_cast<const float4*>(in + (size_t)(row0 + r) * D)[q];
        fT[(q * 4 + 0) * FPAD + r] = v.x;
        fT[(q * 4 + 1) * FPAD + r] = v.y;
        fT[(q * 4 + 2) * FPAD + r] = v.z;
        fT[(q * 4 + 3) * FPAD + r] = v.w;
    }
    __syncthreads();

    const int j0 = (tid & 15) * 4;
    const int r0 = (tid >> 4) * 4;
    float acc[4][4];
    #pragma unroll
    for (int i = 0; i < 4; ++i)
        #pragma unroll
        for (int j = 0; j < 4; ++j) acc[i][j] = 0.f;

    #pragma unroll 8
    for (int k = 0; k < 64; ++k) {
        float4 f = *reinterpret_cast<const float4*>(&fT[k * FPAD + r0]);
        float4 w = *reinterpret_cast<const float4*>(&Wl[k * 64 + j0]);
        float fa[4] = {f.x, f.y, f.z, f.w};
        float wa[4] = {w.x, w.y, w.z, w.w};
        #pragma unroll
        for (int i = 0; i < 4; ++i)
            #pragma unroll
            for (int j = 0; j < 4; ++j) acc[i][j] += fa[i] * wa[j];
    }

    float4 bv = *reinterpret_cast<const float4*>(&b[j0]);
    float ba[4] = {bv.x, bv.y, bv.z, bv.w};
    #pragma unroll
    for (int i = 0; i < 4; ++i) {
        int row = row0 + r0 + i;
        if (row < E) {
            float4 o;
            o.x = relu_f(acc[i][0] + ba[0]);
            o.y = relu_f(acc[i][1] + ba[1]);
            o.z = relu_f(acc[i][2] + ba[2]);
            o.w = relu_f(acc[i][3] + ba[3]);
            *reinterpret_cast<float4*>(outx + (size_t)row * D + j0) = o;
        }
    }
}

// out[e] = relu(concat(x[e], x0[e]) @ W1 + b1) @ W2 + b2
#define MPAD 68
__global__ __launch_bounds__(512) void k_mlp(const float* __restrict__ x,
        const float* __restrict__ x0, const float* __restrict__ W1,
        const float* __restrict__ b1, const float* __restrict__ W2,
        const float* __restrict__ b2, float* __restrict__ out, int E) {
    __shared__ float W1l[128 * 128];
    __shared__ float fT[128 * MPAD];
    __shared__ float b1l[128];
    __shared__ float W2l[128];
    const int tid = threadIdx.x;
    const int row0 = blockIdx.x * 64;

    for (int i = tid; i < 4096; i += 512)
        reinterpret_cast<float4*>(W1l)[i] = reinterpret_cast<const float4*>(W1)[i];
    if (tid < 128) { b1l[tid] = b1[tid]; W2l[tid] = W2[tid]; }

    for (int i = tid; i < 2048; i += 512) {
        int r = i >> 5, q = i & 31;
        int qq = q & 15;
        const float* src = (q < 16) ? x : x0;
        float4 v = make_float4(0.f, 0.f, 0.f, 0.f);
        if (row0 + r < E)
            v = reinterpret_cast<const float4*>(src + (size_t)(row0 + r) * D)[qq];
        int kb = ((q < 16) ? 0 : 64) + qq * 4;
        fT[(kb + 0) * MPAD + r] = v.x;
        fT[(kb + 1) * MPAD + r] = v.y;
        fT[(kb + 2) * MPAD + r] = v.z;
        fT[(kb + 3) * MPAD + r] = v.w;
    }
    __syncthreads();

    const int jt = tid & 31;
    const int j0 = jt * 4;
    const int r0 = (tid >> 5) * 4;
    float acc[4][4];
    #pragma unroll
    for (int i = 0; i < 4; ++i)
        #pragma unroll
        for (int j = 0; j < 4; ++j) acc[i][j] = 0.f;

    #pragma unroll 8
    for (int k = 0; k < 128; ++k) {
        float4 f = *reinterpret_cast<const float4*>(&fT[k * MPAD + r0]);
        float4 w = *reinterpret_cast<const float4*>(&W1l[k * 128 + j0]);
        float fa[4] = {f.x, f.y, f.z, f.w};
        float wa[4] = {w.x, w.y, w.z, w.w};
        #pragma unroll
        for (int i = 0; i < 4; ++i)
            #pragma unroll
            for (int j = 0; j < 4; ++j) acc[i][j] += fa[i] * wa[j];
    }

    float4 bv = *reinterpret_cast<const float4*>(&b1l[j0]);
    float4 w2 = *reinterpret_cast<const float4*>(&W2l[j0]);
    float bias2 = b2[0];
    #pragma unroll
    for (int i = 0; i < 4; ++i) {
        float h0 = relu_f(acc[i][0] + bv.x);
        float h1 = relu_f(acc[i][1] + bv.y);
        float h2 = relu_f(acc[i][2] + bv.z);
        float h3 = relu_f(acc[i][3] + bv.w);
        float p = h0 * w2.x + h1 * w2.y + h2 * w2.z + h3 * w2.w;
        #pragma unroll
        for (int m = 1; m < 32; m <<= 1) p += __shfl_xor(p, m, 64);
        if (jt == 0) {
            int row = row0 + r0 + i;
            if (row < E) out[row] = p + bias2;
        }
    }
}

extern "C" void kernel_launch(void* const* d_in, const int* in_sizes, int n_in,
                              void* d_out, int out_size, void* d_ws, size_t ws_size,
                              hipStream_t stream) {
    const int*   edge_type = (const int*)d_in[0];
    const int*   ab        = (const int*)d_in[1];
    const int*   bc        = (const int*)d_in[2];
    const int*   ac        = (const int*)d_in[3];
    const float* fe        = (const float*)d_in[4];
    const float* W1        = (const float*)d_in[5];
    const float* b1        = (const float*)d_in[6];
    const float* W2        = (const float*)d_in[7];
    const float* b2        = (const float*)d_in[8];
    const float* mW1       = (const float*)d_in[9];
    const float* mb1       = (const float*)d_in[10];
    const float* mW2       = (const float*)d_in[11];
    const float* mb2       = (const float*)d_in[12];

    const int E = in_sizes[0];
    const int T = in_sizes[1];
    float* out = (float*)d_out;

    // workspace layout
    char* p = (char*)d_ws;
    float* x0   = (float*)p;            p += (size_t)E * D * sizeof(float);
    float* x    = (float*)p;            p += (size_t)E * D * sizeof(float);
    float* agg  = (float*)p;            p += (size_t)E * D * sizeof(float);
    int* cnt    = (int*)p;              p += (size_t)E * sizeof(int);
    int* startA = (int*)p;              p += (size_t)E * sizeof(int);
    int* cursor = (int*)p;              p += (size_t)E * sizeof(int);
    int* bsums  = (int*)p;              p += 256 * sizeof(int);
    int* sab    = (int*)p;              p += (size_t)T * sizeof(int);
    int* sbc    = (int*)p;              p += (size_t)T * sizeof(int);

    const int nblkA = (E + 1023) / 1024;

    k_gather<<<(E * 16 + 255) / 256, 256, 0, stream>>>(edge_type, fe, x0, x, E);

    // build CSR of triangles keyed by ac (once; reused by both layers)
    hipMemsetAsync(cnt, 0, (size_t)E * sizeof(int), stream);
    k_hist<<<(T + 255) / 256, 256, 0, stream>>>(ac, cnt, T);
    k_scanA<<<nblkA, 256, 0, stream>>>(cnt, startA, bsums, E);
    k_scanB<<<1, 256, 0, stream>>>(bsums, nblkA);
    k_scanC<<<(E + 255) / 256, 256, 0, stream>>>(startA, bsums, cursor, E);
    k_permute<<<(T + 255) / 256, 256, 0, stream>>>(ab, bc, ac, cursor, sab, sbc, T);

    for (int layer = 0; layer < 2; ++layer) {
        const float* W = (layer == 0) ? W1 : W2;
        const float* b = (layer == 0) ? b1 : b2;
        k_gather_msg<<<(E + 3) / 4, 256, 0, stream>>>(startA, cnt, sab, sbc, x, agg, E);
        k_linear<<<(E + 63) / 64, 256, 0, stream>>>(agg, W, b, x, E);
    }

    k_mlp<<<(E + 63) / 64, 512, 0, stream>>>(x, x0, mW1, mb1, mW2, mb2, out, E);
}